// Round 2
// baseline (2000.101 us; speedup 1.0000x reference)
//
#include <hip/hip_runtime.h>
#include <hip/hip_bf16.h>
#include <stdint.h>

// ---------------------------------------------------------------------------
// E2E: LSTM1(8 steps) -> relu(linear)+BN1 -> concat -> xp2 -> LSTM2 tree(16)
//      -> BN2 -> out [1024,512] float32.
// Inputs are float32 (converted to bf16 during LDS staging); MFMA bf16,
// fp32 accumulate. Runtime flags: flags[0]=mapping-is-int64, flags[1]=f32 io.
// ---------------------------------------------------------------------------

typedef __bf16 bf16;
typedef __bf16 bf16x8 __attribute__((ext_vector_type(8)));
typedef float f32x4 __attribute__((ext_vector_type(4)));

#define HIDDEN 512

__device__ __forceinline__ float sigmoidf_(float x) { return 1.f / (1.f + __expf(-x)); }

// load 8 contiguous elements as bf16x8; src is f32 (convert) or bf16 (direct)
__device__ __forceinline__ bf16x8 load8(const void* p, size_t off, bool f32) {
  if (f32) {
    const float* q = (const float*)p + off;
    float4 a = *(const float4*)q;
    float4 b = *(const float4*)(q + 4);
    bf16x8 r;
    r[0] = (bf16)a.x; r[1] = (bf16)a.y; r[2] = (bf16)a.z; r[3] = (bf16)a.w;
    r[4] = (bf16)b.x; r[5] = (bf16)b.y; r[6] = (bf16)b.z; r[7] = (bf16)b.w;
    return r;
  }
  return *(const bf16x8*)((const bf16*)p + off);
}

__device__ __forceinline__ float ldf(const void* p, int i, bool f32) {
  return f32 ? ((const float*)p)[i] : (float)((const bf16*)p)[i];
}

// ---------------- fused GEMM + LSTM cell ----------------
// Block tile: 128 rows x (32 j x 4 gates). 4 waves 2x2.
// gates = A0·B0^T + A1·B1^T + bias0 + bias1 + xp_add; then LSTM cell.
__global__ __launch_bounds__(256, 2) void cell_gemm(
    const void* __restrict__ A0, int a0off, int a0s, int a0kt, int a0in,
    const void* __restrict__ A1, int a1s, int a1kt, int a1in,
    const void* __restrict__ B0, int b0s,
    const void* __restrict__ B1, int b1s,
    const void* __restrict__ bias0, const void* __restrict__ bias1,
    const bf16* __restrict__ xp_add,          // [M,2048] bf16 ws or null
    const float* __restrict__ c_prev,         // [M,512] or null
    float* __restrict__ c_out,                // [M,512]
    bf16* __restrict__ h_out,                 // [M,512]
    const int* __restrict__ flags)
{
  __shared__ __align__(16) bf16 sA[128 * 32];
  __shared__ __align__(16) bf16 sB[128 * 32];
  const bool inf32 = flags[1] != 0;
  const int tid = threadIdx.x;
  const int lane = tid & 63;
  const int wave = tid >> 6;
  const int wr = wave >> 1, wc = wave & 1;
  const int quad = lane >> 4, cl = lane & 15;
  const int bm0 = blockIdx.x * 128;
  const int j0 = blockIdx.y * 32;

  f32x4 acc[4][4];
#pragma unroll
  for (int mi = 0; mi < 4; ++mi)
#pragma unroll
    for (int g = 0; g < 4; ++g) acc[mi][g] = f32x4{0.f, 0.f, 0.f, 0.f};

  const int nkt = a0kt + a1kt;
  for (int kt = 0; kt < nkt; ++kt) {
#pragma unroll
    for (int it = 0; it < 2; ++it) {
      int e = it * 256 + tid;           // 0..511
      int row = e >> 2, seg = e & 3;
      int wrow = (row >> 5) * HIDDEN + j0 + (row & 31);  // gate*512 + j
      const void* ap; const void* bp;
      size_t aoff, boff;
      bool af32;
      if (kt < a0kt) {
        ap = A0; aoff = (size_t)(bm0 + row) * a0s + a0off + kt * 32 + seg * 8;
        af32 = a0in && inf32;
        bp = B0; boff = (size_t)wrow * b0s + kt * 32 + seg * 8;
      } else {
        ap = A1; aoff = (size_t)(bm0 + row) * a1s + (kt - a0kt) * 32 + seg * 8;
        af32 = a1in && inf32;
        bp = B1; boff = (size_t)wrow * b1s + (kt - a0kt) * 32 + seg * 8;
      }
      *(bf16x8*)&sA[row * 32 + seg * 8] = load8(ap, aoff, af32);
      *(bf16x8*)&sB[row * 32 + seg * 8] = load8(bp, boff, inf32);
    }
    __syncthreads();
    bf16x8 af[4], bfr[4];
#pragma unroll
    for (int mi = 0; mi < 4; ++mi)
      af[mi] = *(const bf16x8*)&sA[(wr * 64 + mi * 16 + cl) * 32 + quad * 8];
#pragma unroll
    for (int g = 0; g < 4; ++g)
      bfr[g] = *(const bf16x8*)&sB[(g * 32 + wc * 16 + cl) * 32 + quad * 8];
#pragma unroll
    for (int mi = 0; mi < 4; ++mi)
#pragma unroll
      for (int g = 0; g < 4; ++g)
        acc[mi][g] = __builtin_amdgcn_mfma_f32_16x16x32_bf16(af[mi], bfr[g], acc[mi][g], 0, 0, 0);
    __syncthreads();
  }

  const int j = j0 + wc * 16 + cl;
  float bI = 0.f, bF = 0.f, bG = 0.f, bO = 0.f;
  if (bias0) {
    bI += ldf(bias0, j, inf32); bF += ldf(bias0, HIDDEN + j, inf32);
    bG += ldf(bias0, 2 * HIDDEN + j, inf32); bO += ldf(bias0, 3 * HIDDEN + j, inf32);
  }
  if (bias1) {
    bI += ldf(bias1, j, inf32); bF += ldf(bias1, HIDDEN + j, inf32);
    bG += ldf(bias1, 2 * HIDDEN + j, inf32); bO += ldf(bias1, 3 * HIDDEN + j, inf32);
  }
#pragma unroll
  for (int mi = 0; mi < 4; ++mi) {
    int rb = bm0 + wr * 64 + mi * 16 + quad * 4;
#pragma unroll
    for (int r = 0; r < 4; ++r) {
      int row = rb + r;
      float gi = acc[mi][0][r] + bI;
      float gf = acc[mi][1][r] + bF;
      float gg = acc[mi][2][r] + bG;
      float go = acc[mi][3][r] + bO;
      if (xp_add) {
        const bf16* xr = xp_add + (size_t)row * 2048;
        gi += (float)xr[j];
        gf += (float)xr[HIDDEN + j];
        gg += (float)xr[2 * HIDDEN + j];
        go += (float)xr[3 * HIDDEN + j];
      }
      float iv = sigmoidf_(gi), fv = sigmoidf_(gf);
      float gv = tanhf(gg), ov = sigmoidf_(go);
      float cp = c_prev ? c_prev[(size_t)row * HIDDEN + j] : 0.f;
      float cn = fv * cp + iv * gv;
      float hn = ov * tanhf(cn);
      c_out[(size_t)row * HIDDEN + j] = cn;
      h_out[(size_t)row * HIDDEN + j] = (bf16)hn;
    }
  }
}

// ---------------- plain GEMM: out_bf16 = concat(A0,A1,A2)·B^T + bias --------
__global__ __launch_bounds__(256, 2) void plain_gemm(
    const void* __restrict__ A0, int a0s, int a0kt, int a0in,
    const void* __restrict__ A1, int a1s, int a1kt, int a1in,
    const void* __restrict__ A2, int a2s, int a2kt, int a2in,
    const void* __restrict__ B, int bs,
    const void* __restrict__ bias,
    int do_relu,
    bf16* __restrict__ outh, int Ntot,
    const int* __restrict__ flags)
{
  __shared__ __align__(16) bf16 sA[128 * 32];
  __shared__ __align__(16) bf16 sB[128 * 32];
  const bool inf32 = flags[1] != 0;
  const int tid = threadIdx.x;
  const int lane = tid & 63;
  const int wave = tid >> 6;
  const int wr = wave >> 1, wc = wave & 1;
  const int quad = lane >> 4, cl = lane & 15;
  const int bm0 = blockIdx.x * 128;
  const int bn0 = blockIdx.y * 128;

  f32x4 acc[4][4];
#pragma unroll
  for (int mi = 0; mi < 4; ++mi)
#pragma unroll
    for (int ni = 0; ni < 4; ++ni) acc[mi][ni] = f32x4{0.f, 0.f, 0.f, 0.f};

  const int nkt = a0kt + a1kt + a2kt;
  for (int kt = 0; kt < nkt; ++kt) {
#pragma unroll
    for (int it = 0; it < 2; ++it) {
      int e = it * 256 + tid;
      int row = e >> 2, seg = e & 3;
      const void* ap; size_t aoff; bool af32;
      if (kt < a0kt) {
        ap = A0; aoff = (size_t)(bm0 + row) * a0s + kt * 32 + seg * 8; af32 = a0in && inf32;
      } else if (kt < a0kt + a1kt) {
        ap = A1; aoff = (size_t)(bm0 + row) * a1s + (kt - a0kt) * 32 + seg * 8; af32 = a1in && inf32;
      } else {
        ap = A2; aoff = (size_t)(bm0 + row) * a2s + (kt - a0kt - a1kt) * 32 + seg * 8; af32 = a2in && inf32;
      }
      size_t boff = (size_t)(bn0 + row) * bs + kt * 32 + seg * 8;
      *(bf16x8*)&sA[row * 32 + seg * 8] = load8(ap, aoff, af32);
      *(bf16x8*)&sB[row * 32 + seg * 8] = load8(B, boff, inf32);
    }
    __syncthreads();
    bf16x8 af[4], bfr[4];
#pragma unroll
    for (int mi = 0; mi < 4; ++mi)
      af[mi] = *(const bf16x8*)&sA[(wr * 64 + mi * 16 + cl) * 32 + quad * 8];
#pragma unroll
    for (int ni = 0; ni < 4; ++ni)
      bfr[ni] = *(const bf16x8*)&sB[(wc * 64 + ni * 16 + cl) * 32 + quad * 8];
#pragma unroll
    for (int mi = 0; mi < 4; ++mi)
#pragma unroll
      for (int ni = 0; ni < 4; ++ni)
        acc[mi][ni] = __builtin_amdgcn_mfma_f32_16x16x32_bf16(af[mi], bfr[ni], acc[mi][ni], 0, 0, 0);
    __syncthreads();
  }

#pragma unroll
  for (int mi = 0; mi < 4; ++mi) {
    int rb = bm0 + wr * 64 + mi * 16 + quad * 4;
#pragma unroll
    for (int ni = 0; ni < 4; ++ni) {
      int col = bn0 + wc * 64 + ni * 16 + cl;
      float bv = bias ? ldf(bias, col, inf32) : 0.f;
#pragma unroll
      for (int r = 0; r < 4; ++r) {
        int row = rb + r;
        float v = acc[mi][ni][r] + bv;
        if (do_relu) v = fmaxf(v, 0.f);
        outh[(size_t)row * Ntot + col] = (bf16)v;
      }
    }
  }
}

// ---------------- tree gather ----------------
__global__ void tree_gather(const int* __restrict__ map, const int* __restrict__ flags,
                            int level,
                            const bf16* __restrict__ h_src, const float* __restrict__ c_src,
                            bf16* __restrict__ h_dst, float* __restrict__ c_dst)
{
  int n = blockIdx.x, t = threadIdx.x;
  int is64 = flags[0];
  long base = (long)level * 2048 + n * 2;
  int m0, m1;
  if (is64) { m0 = map[base * 2]; m1 = map[base * 2 + 2]; }
  else      { m0 = map[base];     m1 = map[base + 1]; }
  float h0 = m0 ? (float)h_src[(size_t)(m0 - 1) * HIDDEN + t] : 0.f;
  float h1v = m1 ? (float)h_src[(size_t)(m1 - 1) * HIDDEN + t] : 0.f;
  float c0 = m0 ? c_src[(size_t)(m0 - 1) * HIDDEN + t] : 0.f;
  float c1v = m1 ? c_src[(size_t)(m1 - 1) * HIDDEN + t] : 0.f;
  h_dst[(size_t)n * HIDDEN + t] = (bf16)(0.5f * (h0 + h1v));
  c_dst[(size_t)n * HIDDEN + t] = 0.5f * (c0 + c1v);
}

// flags[0]: mapping is int64; flags[1]: float tensors are f32
__global__ void detect(const unsigned* __restrict__ mask_words,
                       const int* __restrict__ map, int* __restrict__ flags) {
  __shared__ int any;
  if (threadIdx.x == 0) {
    any = 0;
    flags[1] = (mask_words[0] == 0x3F800000u) ? 1 : 0;
  }
  __syncthreads();
  int loc = 0;
  for (int i = threadIdx.x; i < 16384; i += blockDim.x) loc |= map[2 * i + 1];
  if (loc) atomicOr(&any, 1);
  __syncthreads();
  if (threadIdx.x == 0) flags[0] = (any == 0) ? 1 : 0;
}

// ---------------- batchnorm ----------------
__global__ void zero_f32(float* __restrict__ p, int n) {
  int i = blockIdx.x * blockDim.x + threadIdx.x;
  if (i < n) p[i] = 0.f;
}

__global__ void bn_reduce_b16(const bf16* __restrict__ x, int rows, int F,
                              float* __restrict__ sums) {
  int col = threadIdx.x;
  size_t r0 = (size_t)blockIdx.x * rows;
  float s = 0.f, q = 0.f;
  for (int r = 0; r < rows; ++r) {
    float v = (float)x[(r0 + r) * F + col];
    s += v; q += v * v;
  }
  atomicAdd(&sums[col], s);
  atomicAdd(&sums[F + col], q);
}

__global__ void bn_final(const float* __restrict__ sums, const void* __restrict__ g,
                         const void* __restrict__ b, int F, float invB,
                         float* __restrict__ scale, float* __restrict__ shift,
                         const int* __restrict__ flags) {
  bool inf32 = flags[1] != 0;
  int j = blockIdx.x * blockDim.x + threadIdx.x;
  if (j < F) {
    float mu = sums[j] * invB;
    float var = fmaxf(sums[F + j] * invB - mu * mu, 0.f);
    float sc = ldf(g, j, inf32) * rsqrtf(var + 1e-5f);
    scale[j] = sc;
    shift[j] = ldf(b, j, inf32) - sc * mu;
  }
}

// normalize bf16 ws -> bf16 ws
__global__ void bn_apply_mid(const bf16* __restrict__ x, const float* __restrict__ scale,
                             const float* __restrict__ shift, int Fmask, size_t total,
                             bf16* __restrict__ out) {
  for (size_t i = blockIdx.x * (size_t)blockDim.x + threadIdx.x; i < total;
       i += (size_t)gridDim.x * blockDim.x) {
    int j = (int)(i & (size_t)Fmask);
    out[i] = (bf16)(scale[j] * (float)x[i] + shift[j]);
  }
}

// normalize bf16 ws -> output (dtype per flags[1])
__global__ void bn_apply_out(const bf16* __restrict__ x, const float* __restrict__ scale,
                             const float* __restrict__ shift, int Fmask, size_t total,
                             void* __restrict__ out, const int* __restrict__ flags) {
  bool outf32 = flags[1] != 0;
  for (size_t i = blockIdx.x * (size_t)blockDim.x + threadIdx.x; i < total;
       i += (size_t)gridDim.x * blockDim.x) {
    int j = (int)(i & (size_t)Fmask);
    float v = scale[j] * (float)x[i] + shift[j];
    if (outf32) ((float*)out)[i] = v;
    else        ((bf16*)out)[i] = (bf16)v;
  }
}

// ---------------------------------------------------------------------------
extern "C" void kernel_launch(void* const* d_in, const int* in_sizes, int n_in,
                              void* d_out, int out_size, void* d_ws, size_t ws_size,
                              hipStream_t stream) {
  const void* operators = d_in[0];   // [16,1024,32] f32
  const void* extras    = d_in[1];   // [16,1024,32] f32
  const void* conds     = d_in[2];   // [16,1024,8,256] f32
  const unsigned* masks = (const unsigned*)d_in[3];
  const int*  mapping   = (const int*)d_in[4];
  const void* W1ih = d_in[5];        // [2048,256]
  const void* W1hh = d_in[6];        // [2048,512]
  const void* b1ih = d_in[7];
  const void* b1hh = d_in[8];
  const void* condW = d_in[9];       // [256,512]
  const void* condb = d_in[10];
  const void* bn1g = d_in[11];
  const void* bn1b = d_in[12];
  const void* W2ih = d_in[13];       // [2048,320]
  const void* W2hh = d_in[14];       // [2048,512]
  const void* b2ih = d_in[15];
  const void* b2hh = d_in[16];
  const void* bn2g = d_in[17];
  const void* bn2b = d_in[18];

  char* ws = (char*)d_ws;
  size_t o = 0;
  auto alloc = [&](size_t bytes) {
    char* p = ws + o;
    o += (bytes + 255) & ~(size_t)255;
    return p;
  };
  bf16* h1[2];
  h1[0] = (bf16*)alloc((size_t)16384 * 512 * 2);
  h1[1] = (bf16*)alloc((size_t)16384 * 512 * 2);
  float* c1 = (float*)alloc((size_t)16384 * 512 * 4);
  bf16* last_relu = (bf16*)alloc((size_t)16384 * 256 * 2);
  bf16* last_bn = (bf16*)alloc((size_t)16384 * 256 * 2);
  bf16* xp2 = (bf16*)alloc((size_t)16384 * 2048 * 2);
  bf16* h2a = (bf16*)alloc((size_t)1024 * 512 * 2);
  bf16* h2b = (bf16*)alloc((size_t)1024 * 512 * 2);
  float* c2a = (float*)alloc((size_t)1024 * 512 * 4);
  float* c2b = (float*)alloc((size_t)1024 * 512 * 4);
  float* sums = (float*)alloc(1536 * 4);
  float* scale1 = (float*)alloc(256 * 4);
  float* shift1 = (float*)alloc(256 * 4);
  float* scale2 = (float*)alloc(512 * 4);
  float* shift2 = (float*)alloc(512 * 4);
  int* flags = (int*)alloc(256);
  float* sums1 = sums;
  float* sums2 = sums + 512;

  detect<<<1, 256, 0, stream>>>(masks, mapping, flags);
  zero_f32<<<6, 256, 0, stream>>>(sums, 1536);

  // -------- LSTM1: 8 steps, fused K=768 GEMM + cell --------
  for (int t = 0; t < 8; ++t) {
    const bf16* hprev = (t == 0) ? nullptr : h1[t & 1];
    cell_gemm<<<dim3(128, 16), 256, 0, stream>>>(
        conds, t * 256, 8 * 256, 8, 1,
        hprev, 512, (t == 0) ? 0 : 16, 0,
        W1ih, 256, W1hh, 512,
        b1ih, b1hh,
        nullptr,
        (t == 0) ? nullptr : c1, c1, h1[(t + 1) & 1], flags);
  }

  // -------- last = relu(h1 @ condW^T + condb); BN1 --------
  plain_gemm<<<dim3(128, 2), 256, 0, stream>>>(
      h1[0], 512, 16, 0, nullptr, 0, 0, 0, nullptr, 0, 0, 0,
      condW, 512, condb, 1, last_relu, 256, flags);
  bn_reduce_b16<<<128, 256, 0, stream>>>(last_relu, 128, 256, sums1);
  bn_final<<<1, 256, 0, stream>>>(sums1, bn1g, bn1b, 256, 1.f / 16384.f, scale1, shift1, flags);
  bn_apply_mid<<<1024, 256, 0, stream>>>(last_relu, scale1, shift1, 255,
                                         (size_t)16384 * 256, last_bn);

  // -------- xp2 = concat(op, ex, last_bn) @ W2ih^T + b2ih --------
  plain_gemm<<<dim3(128, 16), 256, 0, stream>>>(
      operators, 32, 1, 1, extras, 32, 1, 1, last_bn, 256, 8, 0,
      W2ih, 320, b2ih, 0, xp2, 2048, flags);

  // -------- LSTM2 tree --------
  cell_gemm<<<dim3(8, 16), 256, 0, stream>>>(
      nullptr, 0, 0, 0, 0, nullptr, 0, 0, 0,
      W2hh, 512, W2hh, 512,
      b2hh, nullptr,
      xp2 + (size_t)15 * 1024 * 2048, nullptr, c2a, h2a, flags);
  for (int idx = 14; idx >= 0; --idx) {
    tree_gather<<<1024, 512, 0, stream>>>(mapping, flags, idx, h2a, c2a, h2b, c2b);
    cell_gemm<<<dim3(8, 16), 256, 0, stream>>>(
        h2b, 0, 512, 16, 0, nullptr, 0, 0, 0,
        W2hh, 512, W2hh, 512,
        b2hh, nullptr,
        xp2 + (size_t)idx * 1024 * 2048, c2b, c2a, h2a, flags);
  }

  // -------- BN2 -> output --------
  bn_reduce_b16<<<32, 512, 0, stream>>>(h2a, 32, 512, sums2);
  bn_final<<<1, 512, 0, stream>>>(sums2, bn2g, bn2b, 512, 1.f / 1024.f, scale2, shift2, flags);
  bn_apply_out<<<512, 256, 0, stream>>>(h2a, scale2, shift2, 511,
                                        (size_t)1024 * 512, d_out, flags);
}

// Round 3
// 1861.175 us; speedup vs baseline: 1.0746x; 1.0746x over previous
//
#include <hip/hip_runtime.h>
#include <hip/hip_bf16.h>
#include <stdint.h>

// ---------------------------------------------------------------------------
// E2E: LSTM1(8 steps) -> relu(linear)+BN1 -> concat -> xp2 -> LSTM2 tree(16)
//      -> BN2 -> out [1024,512] f32.
// f32 inputs converted once to bf16 ws; GEMMs use global_load_lds(16B) staging
// + mfma_f32_16x16x32_bf16, fp32 accum. LSTM2 tree uses split-bf16 (hi/lo) for
// ~fp32 accuracy; tree h/c state kept in f32. Deterministic BN.
// ---------------------------------------------------------------------------

typedef __bf16 bf16;
typedef __bf16 bf16x8 __attribute__((ext_vector_type(8)));
typedef float f32x4 __attribute__((ext_vector_type(4)));

#define HIDDEN 512

__device__ __forceinline__ float sigmoidf_(float x) { return 1.f / (1.f + __expf(-x)); }

__device__ __forceinline__ void async16(const bf16* g, bf16* l) {
  __builtin_amdgcn_global_load_lds(
      (const __attribute__((address_space(1))) void*)g,
      (__attribute__((address_space(3))) void*)l, 16, 0, 0);
}

// ---------------- f32 -> bf16 bulk convert (8 elems/thread) ----------------
__global__ void cvt8(const float* __restrict__ src, bf16* __restrict__ dst) {
  size_t i = ((size_t)blockIdx.x * blockDim.x + threadIdx.x) * 8;
  float4 a = *(const float4*)(src + i);
  float4 b = *(const float4*)(src + i + 4);
  bf16x8 r;
  r[0] = (bf16)a.x; r[1] = (bf16)a.y; r[2] = (bf16)a.z; r[3] = (bf16)a.w;
  r[4] = (bf16)b.x; r[5] = (bf16)b.y; r[6] = (bf16)b.z; r[7] = (bf16)b.w;
  *(bf16x8*)(dst + i) = r;
}

// W2hh f32 [2048x512] -> Wext bf16 [2048x1536] = [W_hi | W_lo | W_hi]
__global__ void build_wext(const float* __restrict__ w, bf16* __restrict__ wext) {
  int r = blockIdx.x, c = threadIdx.x;
  float v = w[(size_t)r * 512 + c];
  bf16 hi = (bf16)v;
  bf16 lo = (bf16)(v - (float)hi);
  bf16* row = wext + (size_t)r * 1536;
  row[c] = hi; row[512 + c] = lo; row[1024 + c] = hi;
}

// flags[0] = mapping is int64
__global__ void detect(const int* __restrict__ map, int* __restrict__ flags) {
  __shared__ int any;
  if (threadIdx.x == 0) any = 0;
  __syncthreads();
  int loc = 0;
  for (int i = threadIdx.x; i < 16384; i += blockDim.x) loc |= map[2 * i + 1];
  if (loc) atomicOr(&any, 1);
  __syncthreads();
  if (threadIdx.x == 0) flags[0] = (any == 0) ? 1 : 0;
}

// ---------------- fused GEMM + LSTM cell (pure bf16 inputs) ----------------
// Block: 128 rows x (32 j x 4 gates). A = [A0-kts | A1-kts], B likewise.
__global__ __launch_bounds__(256, 2) void cell_gemm(
    const bf16* __restrict__ A0, int a0off, int a0s, int a0kt,
    const bf16* __restrict__ A1, int a1s, int a1kt,
    const bf16* __restrict__ B0, int b0s,
    const bf16* __restrict__ B1, int b1s,
    const float* __restrict__ bias0, const float* __restrict__ bias1,
    const void* __restrict__ xp_add, int xp_f32,   // [M,2048] or null
    const float* __restrict__ c_prev,              // [M,512] or null
    float* __restrict__ c_out,
    bf16* __restrict__ h_b16, float* __restrict__ h_f32)
{
  __shared__ __align__(16) bf16 sA[128 * 32];
  __shared__ __align__(16) bf16 sB[128 * 32];
  const int tid = threadIdx.x;
  const int lane = tid & 63;
  const int quad = lane >> 4, cl = lane & 15;
  const int wave = tid >> 6;
  const int wr = wave >> 1, wc = wave & 1;
  const int bm0 = blockIdx.x * 128;
  const int j0 = blockIdx.y * 32;

  f32x4 acc[4][4];
#pragma unroll
  for (int mi = 0; mi < 4; ++mi)
#pragma unroll
    for (int g = 0; g < 4; ++g) acc[mi][g] = f32x4{0.f, 0.f, 0.f, 0.f};

  const int nkt = a0kt + a1kt;
  for (int kt = 0; kt < nkt; ++kt) {
    const bf16* abase; int astr, acol;
    const bf16* bbase; int bstr, bcol;
    if (kt < a0kt) {
      abase = A0; astr = a0s; acol = a0off + kt * 32;
      bbase = B0; bstr = b0s; bcol = kt * 32;
    } else {
      abase = A1; astr = a1s; acol = (kt - a0kt) * 32;
      bbase = B1; bstr = b1s; bcol = (kt - a0kt) * 32;
    }
#pragma unroll
    for (int it = 0; it < 2; ++it) {
      int e = it * 256 + tid;
      int row = e >> 2, seg = e & 3;
      int wbase = it * 256 + (tid & ~63);       // wave-uniform 16B-seg index
      async16(abase + (size_t)(bm0 + row) * astr + acol + seg * 8, sA + wbase * 8);
      int wrow = (row >> 5) * HIDDEN + j0 + (row & 31);  // gate*512 + j
      async16(bbase + (size_t)wrow * bstr + bcol + seg * 8, sB + wbase * 8);
    }
    __syncthreads();
    bf16x8 af[4], bfr[4];
#pragma unroll
    for (int mi = 0; mi < 4; ++mi)
      af[mi] = *(const bf16x8*)&sA[(wr * 64 + mi * 16 + cl) * 32 + quad * 8];
#pragma unroll
    for (int g = 0; g < 4; ++g)
      bfr[g] = *(const bf16x8*)&sB[(g * 32 + wc * 16 + cl) * 32 + quad * 8];
#pragma unroll
    for (int mi = 0; mi < 4; ++mi)
#pragma unroll
      for (int g = 0; g < 4; ++g)
        acc[mi][g] = __builtin_amdgcn_mfma_f32_16x16x32_bf16(af[mi], bfr[g], acc[mi][g], 0, 0, 0);
    __syncthreads();
  }

  const int j = j0 + wc * 16 + cl;
  float bI = 0.f, bF = 0.f, bG = 0.f, bO = 0.f;
  if (bias0) {
    bI += bias0[j]; bF += bias0[HIDDEN + j];
    bG += bias0[2 * HIDDEN + j]; bO += bias0[3 * HIDDEN + j];
  }
  if (bias1) {
    bI += bias1[j]; bF += bias1[HIDDEN + j];
    bG += bias1[2 * HIDDEN + j]; bO += bias1[3 * HIDDEN + j];
  }
#pragma unroll
  for (int mi = 0; mi < 4; ++mi) {
    int rb = bm0 + wr * 64 + mi * 16 + quad * 4;
#pragma unroll
    for (int r = 0; r < 4; ++r) {
      int row = rb + r;
      float gi = acc[mi][0][r] + bI;
      float gf = acc[mi][1][r] + bF;
      float gg = acc[mi][2][r] + bG;
      float go = acc[mi][3][r] + bO;
      if (xp_add) {
        size_t base = (size_t)row * 2048;
        if (xp_f32) {
          const float* xr = (const float*)xp_add + base;
          gi += xr[j]; gf += xr[HIDDEN + j];
          gg += xr[2 * HIDDEN + j]; go += xr[3 * HIDDEN + j];
        } else {
          const bf16* xr = (const bf16*)xp_add + base;
          gi += (float)xr[j]; gf += (float)xr[HIDDEN + j];
          gg += (float)xr[2 * HIDDEN + j]; go += (float)xr[3 * HIDDEN + j];
        }
      }
      float iv = sigmoidf_(gi), fv = sigmoidf_(gf);
      float gv = tanhf(gg), ov = sigmoidf_(go);
      float cp = c_prev ? c_prev[(size_t)row * HIDDEN + j] : 0.f;
      float cn = fv * cp + iv * gv;
      float hn = ov * tanhf(cn);
      c_out[(size_t)row * HIDDEN + j] = cn;
      if (h_b16) h_b16[(size_t)row * HIDDEN + j] = (bf16)hn;
      if (h_f32) h_f32[(size_t)row * HIDDEN + j] = hn;
    }
  }
}

// ---------------- plain GEMM: concat(A0,A1,A2)·B^T + bias [relu] -----------
__global__ __launch_bounds__(256, 2) void plain_gemm(
    const bf16* __restrict__ A0, int a0s, int a0kt,
    const bf16* __restrict__ A1, int a1s, int a1kt,
    const bf16* __restrict__ A2, int a2s, int a2kt,
    const bf16* __restrict__ B, int bs,
    const float* __restrict__ bias, int do_relu,
    bf16* __restrict__ outh, float* __restrict__ outf, int Ntot)
{
  __shared__ __align__(16) bf16 sA[128 * 32];
  __shared__ __align__(16) bf16 sB[128 * 32];
  const int tid = threadIdx.x;
  const int lane = tid & 63;
  const int quad = lane >> 4, cl = lane & 15;
  const int wave = tid >> 6;
  const int wr = wave >> 1, wc = wave & 1;
  const int bm0 = blockIdx.x * 128;
  const int bn0 = blockIdx.y * 128;

  f32x4 acc[4][4];
#pragma unroll
  for (int mi = 0; mi < 4; ++mi)
#pragma unroll
    for (int ni = 0; ni < 4; ++ni) acc[mi][ni] = f32x4{0.f, 0.f, 0.f, 0.f};

  const int nkt = a0kt + a1kt + a2kt;
  for (int kt = 0; kt < nkt; ++kt) {
    const bf16* abase; int astr, acol;
    if (kt < a0kt)            { abase = A0; astr = a0s; acol = kt * 32; }
    else if (kt < a0kt + a1kt){ abase = A1; astr = a1s; acol = (kt - a0kt) * 32; }
    else                      { abase = A2; astr = a2s; acol = (kt - a0kt - a1kt) * 32; }
#pragma unroll
    for (int it = 0; it < 2; ++it) {
      int e = it * 256 + tid;
      int row = e >> 2, seg = e & 3;
      int wbase = it * 256 + (tid & ~63);
      async16(abase + (size_t)(bm0 + row) * astr + acol + seg * 8, sA + wbase * 8);
      async16(B + (size_t)(bn0 + row) * bs + kt * 32 + seg * 8, sB + wbase * 8);
    }
    __syncthreads();
    bf16x8 af[4], bfr[4];
#pragma unroll
    for (int mi = 0; mi < 4; ++mi)
      af[mi] = *(const bf16x8*)&sA[(wr * 64 + mi * 16 + cl) * 32 + quad * 8];
#pragma unroll
    for (int ni = 0; ni < 4; ++ni)
      bfr[ni] = *(const bf16x8*)&sB[(wc * 64 + ni * 16 + cl) * 32 + quad * 8];
#pragma unroll
    for (int mi = 0; mi < 4; ++mi)
#pragma unroll
      for (int ni = 0; ni < 4; ++ni)
        acc[mi][ni] = __builtin_amdgcn_mfma_f32_16x16x32_bf16(af[mi], bfr[ni], acc[mi][ni], 0, 0, 0);
    __syncthreads();
  }

#pragma unroll
  for (int mi = 0; mi < 4; ++mi) {
    int rb = bm0 + wr * 64 + mi * 16 + quad * 4;
#pragma unroll
    for (int ni = 0; ni < 4; ++ni) {
      int col = bn0 + wc * 64 + ni * 16 + cl;
      float bv = bias ? bias[col] : 0.f;
#pragma unroll
      for (int r = 0; r < 4; ++r) {
        int row = rb + r;
        float v = acc[mi][ni][r] + bv;
        if (do_relu) v = fmaxf(v, 0.f);
        if (outf) outf[(size_t)row * Ntot + col] = v;
        else      outh[(size_t)row * Ntot + col] = (bf16)v;
      }
    }
  }
}

// ---------------- tree: gather + hi/lo split ----------------
// hA[n, 0:512]=hi, hA[n, 512:1024]=lo of 0.5*(h[m0]+h[m1]); c likewise avg.
__global__ void gather_split(const int* __restrict__ map, const int* __restrict__ flags,
                             int level,
                             const float* __restrict__ h_src, const float* __restrict__ c_src,
                             bf16* __restrict__ hA, float* __restrict__ c_dst)
{
  int n = blockIdx.x, t = threadIdx.x;
  long base = (long)level * 2048 + n * 2;
  int m0, m1;
  if (flags[0]) { m0 = map[base * 2]; m1 = map[base * 2 + 2]; }
  else          { m0 = map[base];     m1 = map[base + 1]; }
  float h0 = m0 ? h_src[(size_t)(m0 - 1) * HIDDEN + t] : 0.f;
  float h1 = m1 ? h_src[(size_t)(m1 - 1) * HIDDEN + t] : 0.f;
  float c0 = m0 ? c_src[(size_t)(m0 - 1) * HIDDEN + t] : 0.f;
  float c1 = m1 ? c_src[(size_t)(m1 - 1) * HIDDEN + t] : 0.f;
  float hv = 0.5f * (h0 + h1);
  bf16 hi = (bf16)hv;
  hA[(size_t)n * 1024 + t] = hi;
  hA[(size_t)n * 1024 + 512 + t] = (bf16)(hv - (float)hi);
  c_dst[(size_t)n * HIDDEN + t] = 0.5f * (c0 + c1);
}

// level-15 cell: zero state -> gates = xp2[15] + bhh
__global__ void cell0(const void* __restrict__ xp, int xp_f32,
                      const float* __restrict__ bhh,
                      float* __restrict__ h, float* __restrict__ c)
{
  int n = blockIdx.x, j = threadIdx.x;
  float g[4];
#pragma unroll
  for (int k = 0; k < 4; ++k) {
    size_t idx = (size_t)n * 2048 + k * 512 + j;
    float v = xp_f32 ? ((const float*)xp)[idx] : (float)((const bf16*)xp)[idx];
    g[k] = v + bhh[k * 512 + j];
  }
  float cv = sigmoidf_(g[0]) * tanhf(g[2]);
  h[(size_t)n * HIDDEN + j] = sigmoidf_(g[3]) * tanhf(cv);
  c[(size_t)n * HIDDEN + j] = cv;
}

// ---------------- deterministic batchnorm ----------------
__global__ void bn_reduce_b16(const bf16* __restrict__ x, int rpb, int F,
                              float* __restrict__ partials) {
  int col = threadIdx.x, b = blockIdx.x;
  const bf16* p = x + (size_t)b * rpb * F + col;
  float s = 0.f, q = 0.f;
  for (int r = 0; r < rpb; ++r) { float v = (float)p[(size_t)r * F]; s += v; q += v * v; }
  partials[(size_t)b * 2 * F + col] = s;
  partials[(size_t)b * 2 * F + F + col] = q;
}

__global__ void bn_reduce_f32(const float* __restrict__ x, int rpb, int F,
                              float* __restrict__ partials) {
  int col = threadIdx.x, b = blockIdx.x;
  const float* p = x + (size_t)b * rpb * F + col;
  float s = 0.f, q = 0.f;
  for (int r = 0; r < rpb; ++r) { float v = p[(size_t)r * F]; s += v; q += v * v; }
  partials[(size_t)b * 2 * F + col] = s;
  partials[(size_t)b * 2 * F + F + col] = q;
}

__global__ void bn_final(const float* __restrict__ partials, int nb, int F,
                         const float* __restrict__ g, const float* __restrict__ b,
                         float invB, float* __restrict__ scale, float* __restrict__ shift) {
  int j = threadIdx.x;
  float s = 0.f, q = 0.f;
  for (int i = 0; i < nb; ++i) {
    s += partials[(size_t)i * 2 * F + j];
    q += partials[(size_t)i * 2 * F + F + j];
  }
  float mu = s * invB;
  float var = fmaxf(q * invB - mu * mu, 0.f);
  float sc = g[j] * rsqrtf(var + 1e-5f);
  scale[j] = sc;
  shift[j] = b[j] - sc * mu;
}

__global__ void bn_apply_mid(const bf16* __restrict__ x, const float* __restrict__ scale,
                             const float* __restrict__ shift, int Fmask, size_t total,
                             bf16* __restrict__ out) {
  for (size_t i = blockIdx.x * (size_t)blockDim.x + threadIdx.x; i < total;
       i += (size_t)gridDim.x * blockDim.x) {
    int j = (int)(i & (size_t)Fmask);
    out[i] = (bf16)(scale[j] * (float)x[i] + shift[j]);
  }
}

__global__ void bn_apply_out(const float* __restrict__ x, const float* __restrict__ scale,
                             const float* __restrict__ shift, int Fmask, size_t total,
                             float* __restrict__ out) {
  for (size_t i = blockIdx.x * (size_t)blockDim.x + threadIdx.x; i < total;
       i += (size_t)gridDim.x * blockDim.x) {
    int j = (int)(i & (size_t)Fmask);
    out[i] = scale[j] * x[i] + shift[j];
  }
}

// ---------------------------------------------------------------------------
extern "C" void kernel_launch(void* const* d_in, const int* in_sizes, int n_in,
                              void* d_out, int out_size, void* d_ws, size_t ws_size,
                              hipStream_t stream) {
  const float* operators = (const float*)d_in[0];   // [16,1024,32]
  const float* extras    = (const float*)d_in[1];
  const float* conds     = (const float*)d_in[2];   // [16,1024,8,256]
  const int*   mapping   = (const int*)d_in[4];
  const float* W1ih = (const float*)d_in[5];
  const float* W1hh = (const float*)d_in[6];
  const float* b1ih = (const float*)d_in[7];
  const float* b1hh = (const float*)d_in[8];
  const float* condW = (const float*)d_in[9];
  const float* condb = (const float*)d_in[10];
  const float* bn1g = (const float*)d_in[11];
  const float* bn1b = (const float*)d_in[12];
  const float* W2ih = (const float*)d_in[13];
  const float* W2hh = (const float*)d_in[14];
  const float* b2ih = (const float*)d_in[15];
  const float* b2hh = (const float*)d_in[16];
  const float* bn2g = (const float*)d_in[17];
  const float* bn2b = (const float*)d_in[18];

  char* ws = (char*)d_ws;
  size_t o = 0;
  auto alloc = [&](size_t bytes) {
    char* p = ws + o;
    o += (bytes + 255) & ~(size_t)255;
    return p;
  };
  bf16* conds_b = (bf16*)alloc((size_t)33554432 * 2);
  bf16* ops_b   = (bf16*)alloc((size_t)524288 * 2);
  bf16* ext_b   = (bf16*)alloc((size_t)524288 * 2);
  bf16* w1ih_b  = (bf16*)alloc((size_t)524288 * 2);
  bf16* w1hh_b  = (bf16*)alloc((size_t)1048576 * 2);
  bf16* condw_b = (bf16*)alloc((size_t)131072 * 2);
  bf16* w2ih_b  = (bf16*)alloc((size_t)655360 * 2);
  bf16* wext    = (bf16*)alloc((size_t)2048 * 1536 * 2);
  bf16* h1[2];
  h1[0] = (bf16*)alloc((size_t)16384 * 512 * 2);
  h1[1] = (bf16*)alloc((size_t)16384 * 512 * 2);
  float* c1 = (float*)alloc((size_t)16384 * 512 * 4);
  bf16* last_relu = (bf16*)alloc((size_t)16384 * 256 * 2);
  bf16* last_bn = (bf16*)alloc((size_t)16384 * 256 * 2);
  float* h2 = (float*)alloc((size_t)1024 * 512 * 4);
  bf16* hA = (bf16*)alloc((size_t)1024 * 1024 * 2);
  float* c2a = (float*)alloc((size_t)1024 * 512 * 4);
  float* c2b = (float*)alloc((size_t)1024 * 512 * 4);
  float* partials = (float*)alloc((size_t)64 * 1024 * 4);
  float* scale1 = (float*)alloc(256 * 4);
  float* shift1 = (float*)alloc(256 * 4);
  float* scale2 = (float*)alloc(512 * 4);
  float* shift2 = (float*)alloc(512 * 4);
  int* flags = (int*)alloc(256);

  // xp2: f32 if workspace allows, else bf16 (precision fallback)
  size_t xp2_elems = (size_t)16384 * 2048;
  int xpf = (o + xp2_elems * 4 <= ws_size) ? 1 : 0;
  void* xp2 = alloc(xp2_elems * (xpf ? 4 : 2));
  float* xp2f = xpf ? (float*)xp2 : nullptr;
  bf16* xp2h = xpf ? nullptr : (bf16*)xp2;

  detect<<<1, 256, 0, stream>>>(mapping, flags);
  cvt8<<<16384, 256, 0, stream>>>(conds, conds_b);
  cvt8<<<256, 256, 0, stream>>>(operators, ops_b);
  cvt8<<<256, 256, 0, stream>>>(extras, ext_b);
  cvt8<<<256, 256, 0, stream>>>(W1ih, w1ih_b);
  cvt8<<<512, 256, 0, stream>>>(W1hh, w1hh_b);
  cvt8<<<64, 256, 0, stream>>>(condW, condw_b);
  cvt8<<<320, 256, 0, stream>>>(W2ih, w2ih_b);
  build_wext<<<2048, 512, 0, stream>>>(W2hh, wext);

  // -------- LSTM1: 8 fused K=768 GEMM+cell steps --------
  for (int t = 0; t < 8; ++t) {
    const bf16* hprev = (t == 0) ? nullptr : h1[t & 1];
    cell_gemm<<<dim3(128, 16), 256, 0, stream>>>(
        conds_b, t * 256, 2048, 8,
        hprev, 512, (t == 0) ? 0 : 16,
        w1ih_b, 256, w1hh_b, 512,
        b1ih, b1hh,
        nullptr, 0,
        (t == 0) ? nullptr : c1, c1, h1[(t + 1) & 1], nullptr);
  }

  // -------- last = relu(h1 @ condW^T + condb); BN1 --------
  plain_gemm<<<dim3(128, 2), 256, 0, stream>>>(
      h1[0], 512, 16, nullptr, 0, 0, nullptr, 0, 0,
      condw_b, 512, condb, 1, last_relu, nullptr, 256);
  bn_reduce_b16<<<64, 256, 0, stream>>>(last_relu, 256, 256, partials);
  bn_final<<<1, 256, 0, stream>>>(partials, 64, 256, bn1g, bn1b, 1.f / 16384.f, scale1, shift1);
  bn_apply_mid<<<1024, 256, 0, stream>>>(last_relu, scale1, shift1, 255,
                                         (size_t)16384 * 256, last_bn);

  // -------- xp2 = concat(ops, extras, last_bn) @ W2ih^T + b2ih --------
  plain_gemm<<<dim3(128, 16), 256, 0, stream>>>(
      ops_b, 32, 1, ext_b, 32, 1, last_bn, 256, 8,
      w2ih_b, 320, b2ih, 0, xp2h, xp2f, 2048);

  // -------- LSTM2 tree --------
  size_t lvl_sz = (size_t)1024 * 2048;
  const void* xp15 = xpf ? (const void*)(xp2f + 15 * lvl_sz) : (const void*)(xp2h + 15 * lvl_sz);
  cell0<<<1024, 512, 0, stream>>>(xp15, xpf, b2hh, h2, c2a);
  for (int idx = 14; idx >= 0; --idx) {
    gather_split<<<1024, 512, 0, stream>>>(mapping, flags, idx, h2, c2a, hA, c2b);
    const void* xpl = xpf ? (const void*)(xp2f + idx * lvl_sz) : (const void*)(xp2h + idx * lvl_sz);
    // split-bf16: gates = hA_hi·Whi + hA_hi·Wlo + hA_lo·Whi  (K = 48 tiles)
    cell_gemm<<<dim3(8, 16), 256, 0, stream>>>(
        hA, 0, 1024, 16,
        hA, 1024, 32,
        wext, 1536, wext + 512, 1536,
        b2hh, nullptr,
        xpl, xpf,
        c2b, c2a, nullptr, h2);
  }

  // -------- BN2 -> output --------
  bn_reduce_f32<<<16, 512, 0, stream>>>(h2, 64, 512, partials);
  bn_final<<<1, 512, 0, stream>>>(partials, 16, 512, bn2g, bn2b, 1.f / 1024.f, scale2, shift2);
  bn_apply_out<<<512, 256, 0, stream>>>(h2, scale2, shift2, 511,
                                        (size_t)1024 * 512, (float*)d_out);
}

// Round 4
// 1303.620 us; speedup vs baseline: 1.5343x; 1.4277x over previous
//
#include <hip/hip_runtime.h>
#include <hip/hip_bf16.h>
#include <stdint.h>

// ---------------------------------------------------------------------------
// E2E: LSTM1(8 steps) -> relu(linear)+BN1 -> concat -> xp2 -> LSTM2 tree(16)
//      -> BN2 -> out [1024,512] f32.
// bf16 MFMA (fp32 accum), global_load_lds(16B) staging with XOR bank swizzle,
// BK=64 in cell_gemm. Tree = plain bf16 K=512 (precision measured upstream-
// dominated; split-bf16 tree bought nothing in round 3).
// ---------------------------------------------------------------------------

typedef __bf16 bf16;
typedef __bf16 bf16x8 __attribute__((ext_vector_type(8)));
typedef float f32x4 __attribute__((ext_vector_type(4)));

#define HIDDEN 512

__device__ __forceinline__ float sigmoidf_(float x) { return 1.f / (1.f + __expf(-x)); }

__device__ __forceinline__ void async16(const bf16* g, bf16* l) {
  __builtin_amdgcn_global_load_lds(
      (const __attribute__((address_space(1))) void*)g,
      (__attribute__((address_space(3))) void*)l, 16, 0, 0);
}

// ---------------- f32 -> bf16 bulk convert (8 elems/thread) ----------------
__global__ void cvt8(const float* __restrict__ src, bf16* __restrict__ dst) {
  size_t i = ((size_t)blockIdx.x * blockDim.x + threadIdx.x) * 8;
  float4 a = *(const float4*)(src + i);
  float4 b = *(const float4*)(src + i + 4);
  bf16x8 r;
  r[0] = (bf16)a.x; r[1] = (bf16)a.y; r[2] = (bf16)a.z; r[3] = (bf16)a.w;
  r[4] = (bf16)b.x; r[5] = (bf16)b.y; r[6] = (bf16)b.z; r[7] = (bf16)b.w;
  *(bf16x8*)(dst + i) = r;
}

// flags[0] = mapping is int64
__global__ void detect(const int* __restrict__ map, int* __restrict__ flags) {
  __shared__ int any;
  if (threadIdx.x == 0) any = 0;
  __syncthreads();
  int loc = 0;
  for (int i = threadIdx.x; i < 16384; i += blockDim.x) loc |= map[2 * i + 1];
  if (loc) atomicOr(&any, 1);
  __syncthreads();
  if (threadIdx.x == 0) flags[0] = (any == 0) ? 1 : 0;
}

// ---------------- fused GEMM + LSTM cell, BK=64, swizzled LDS --------------
// Block: (MT*32) rows x (32 j x 4 gates). 4 waves 2x2. kt counts in K=64 units.
// LDS row = 64 bf16 (128 B = all 32 banks); slot s holds global seg s^(row&7)
// so 16 cl-lanes of a fragment read spread over all 8 bank groups (2-way, free).
template <int MT>
__global__ __launch_bounds__(256, 2) void cell_gemm(
    const bf16* __restrict__ A0, int a0off, int a0s, int a0kt,
    const bf16* __restrict__ A1, int a1s, int a1kt,
    const bf16* __restrict__ B0, int b0s,
    const bf16* __restrict__ B1, int b1s,
    const float* __restrict__ bias0, const float* __restrict__ bias1,
    const void* __restrict__ xp_add, int xp_f32,   // [M,2048] or null
    const float* __restrict__ c_prev,              // [M,512] or null
    float* __restrict__ c_out,
    bf16* __restrict__ h_b16, float* __restrict__ h_f32)
{
  constexpr int BM = MT * 32;
  __shared__ __align__(16) bf16 sA[BM * 64];
  __shared__ __align__(16) bf16 sB[128 * 64];
  const int tid = threadIdx.x;
  const int lane = tid & 63;
  const int quad = lane >> 4, cl = lane & 15;
  const int wave = tid >> 6;
  const int wr = wave >> 1, wc = wave & 1;
  const int bm0 = blockIdx.x * BM;
  const int j0 = blockIdx.y * 32;

  f32x4 acc[MT][4];
#pragma unroll
  for (int mi = 0; mi < MT; ++mi)
#pragma unroll
    for (int g = 0; g < 4; ++g) acc[mi][g] = f32x4{0.f, 0.f, 0.f, 0.f};

  const int nkt = a0kt + a1kt;
  for (int kt = 0; kt < nkt; ++kt) {
    const bf16* abase; int astr, acol;
    const bf16* bbase; int bstr, bcol;
    if (kt < a0kt) {
      abase = A0; astr = a0s; acol = a0off + kt * 64;
      bbase = B0; bstr = b0s; bcol = kt * 64;
    } else {
      abase = A1; astr = a1s; acol = (kt - a0kt) * 64;
      bbase = B1; bstr = b1s; bcol = (kt - a0kt) * 64;
    }
#pragma unroll
    for (int ia = 0; ia < MT; ++ia) {
      int e = ia * 256 + tid;
      int row = e >> 3, sl = e & 7;
      int src = sl ^ (row & 7);
      async16(abase + (size_t)(bm0 + row) * astr + acol + src * 8, sA + e * 8);
    }
#pragma unroll
    for (int ib = 0; ib < 4; ++ib) {
      int e = ib * 256 + tid;
      int row = e >> 3, sl = e & 7;
      int src = sl ^ (row & 7);
      int wrow = (row >> 5) * HIDDEN + j0 + (row & 31);  // gate*512 + j
      async16(bbase + (size_t)wrow * bstr + bcol + src * 8, sB + e * 8);
    }
    __syncthreads();
#pragma unroll
    for (int kh = 0; kh < 2; ++kh) {
      bf16x8 af[MT], bfr[4];
#pragma unroll
      for (int mi = 0; mi < MT; ++mi) {
        int row = wr * (MT * 16) + mi * 16 + cl;
        int sl = (kh * 4 + quad) ^ (row & 7);
        af[mi] = *(const bf16x8*)&sA[row * 64 + sl * 8];
      }
#pragma unroll
      for (int g = 0; g < 4; ++g) {
        int row = g * 32 + wc * 16 + cl;
        int sl = (kh * 4 + quad) ^ (row & 7);
        bfr[g] = *(const bf16x8*)&sB[row * 64 + sl * 8];
      }
#pragma unroll
      for (int mi = 0; mi < MT; ++mi)
#pragma unroll
        for (int g = 0; g < 4; ++g)
          acc[mi][g] = __builtin_amdgcn_mfma_f32_16x16x32_bf16(af[mi], bfr[g], acc[mi][g], 0, 0, 0);
    }
    __syncthreads();
  }

  const int j = j0 + wc * 16 + cl;
  float bI = 0.f, bF = 0.f, bG = 0.f, bO = 0.f;
  if (bias0) {
    bI += bias0[j]; bF += bias0[HIDDEN + j];
    bG += bias0[2 * HIDDEN + j]; bO += bias0[3 * HIDDEN + j];
  }
  if (bias1) {
    bI += bias1[j]; bF += bias1[HIDDEN + j];
    bG += bias1[2 * HIDDEN + j]; bO += bias1[3 * HIDDEN + j];
  }
#pragma unroll
  for (int mi = 0; mi < MT; ++mi) {
    int rb = bm0 + wr * (MT * 16) + mi * 16 + quad * 4;
#pragma unroll
    for (int r = 0; r < 4; ++r) {
      int row = rb + r;
      float gi = acc[mi][0][r] + bI;
      float gf = acc[mi][1][r] + bF;
      float gg = acc[mi][2][r] + bG;
      float go = acc[mi][3][r] + bO;
      if (xp_add) {
        size_t base = (size_t)row * 2048;
        if (xp_f32) {
          const float* xr = (const float*)xp_add + base;
          gi += xr[j]; gf += xr[HIDDEN + j];
          gg += xr[2 * HIDDEN + j]; go += xr[3 * HIDDEN + j];
        } else {
          const bf16* xr = (const bf16*)xp_add + base;
          gi += (float)xr[j]; gf += (float)xr[HIDDEN + j];
          gg += (float)xr[2 * HIDDEN + j]; go += (float)xr[3 * HIDDEN + j];
        }
      }
      float iv = sigmoidf_(gi), fv = sigmoidf_(gf);
      float gv = tanhf(gg), ov = sigmoidf_(go);
      float cp = c_prev ? c_prev[(size_t)row * HIDDEN + j] : 0.f;
      float cn = fv * cp + iv * gv;
      float hn = ov * tanhf(cn);
      c_out[(size_t)row * HIDDEN + j] = cn;
      if (h_b16) h_b16[(size_t)row * HIDDEN + j] = (bf16)hn;
      if (h_f32) h_f32[(size_t)row * HIDDEN + j] = hn;
    }
  }
}

// ---------------- plain GEMM (BK=32, swizzled): concat(A0,A1,A2)·B^T -------
__global__ __launch_bounds__(256, 2) void plain_gemm(
    const bf16* __restrict__ A0, int a0s, int a0kt,
    const bf16* __restrict__ A1, int a1s, int a1kt,
    const bf16* __restrict__ A2, int a2s, int a2kt,
    const bf16* __restrict__ B, int bs,
    const float* __restrict__ bias, int do_relu,
    bf16* __restrict__ outh, float* __restrict__ outf, int Ntot)
{
  __shared__ __align__(16) bf16 sA[128 * 32];
  __shared__ __align__(16) bf16 sB[128 * 32];
  const int tid = threadIdx.x;
  const int lane = tid & 63;
  const int quad = lane >> 4, cl = lane & 15;
  const int wave = tid >> 6;
  const int wr = wave >> 1, wc = wave & 1;
  const int bm0 = blockIdx.x * 128;
  const int bn0 = blockIdx.y * 128;

  f32x4 acc[4][4];
#pragma unroll
  for (int mi = 0; mi < 4; ++mi)
#pragma unroll
    for (int ni = 0; ni < 4; ++ni) acc[mi][ni] = f32x4{0.f, 0.f, 0.f, 0.f};

  const int nkt = a0kt + a1kt + a2kt;
  for (int kt = 0; kt < nkt; ++kt) {
    const bf16* abase; int astr, acol;
    if (kt < a0kt)            { abase = A0; astr = a0s; acol = kt * 32; }
    else if (kt < a0kt + a1kt){ abase = A1; astr = a1s; acol = (kt - a0kt) * 32; }
    else                      { abase = A2; astr = a2s; acol = (kt - a0kt - a1kt) * 32; }
#pragma unroll
    for (int it = 0; it < 2; ++it) {
      int e = it * 256 + tid;
      int row = e >> 2, sl = e & 3;
      int src = sl ^ ((row >> 1) & 3);
      async16(abase + (size_t)(bm0 + row) * astr + acol + src * 8, sA + e * 8);
      async16(B + (size_t)(bn0 + row) * bs + kt * 32 + src * 8, sB + e * 8);
    }
    __syncthreads();
    bf16x8 af[4], bfr[4];
#pragma unroll
    for (int mi = 0; mi < 4; ++mi) {
      int row = wr * 64 + mi * 16 + cl;
      int sl = quad ^ ((row >> 1) & 3);
      af[mi] = *(const bf16x8*)&sA[row * 32 + sl * 8];
    }
#pragma unroll
    for (int ni = 0; ni < 4; ++ni) {
      int row = wc * 64 + ni * 16 + cl;
      int sl = quad ^ ((row >> 1) & 3);
      bfr[ni] = *(const bf16x8*)&sB[row * 32 + sl * 8];
    }
#pragma unroll
    for (int mi = 0; mi < 4; ++mi)
#pragma unroll
      for (int ni = 0; ni < 4; ++ni)
        acc[mi][ni] = __builtin_amdgcn_mfma_f32_16x16x32_bf16(af[mi], bfr[ni], acc[mi][ni], 0, 0, 0);
    __syncthreads();
  }

#pragma unroll
  for (int mi = 0; mi < 4; ++mi) {
    int rb = bm0 + wr * 64 + mi * 16 + quad * 4;
#pragma unroll
    for (int ni = 0; ni < 4; ++ni) {
      int col = bn0 + wc * 64 + ni * 16 + cl;
      float bv = bias ? bias[col] : 0.f;
#pragma unroll
      for (int r = 0; r < 4; ++r) {
        int row = rb + r;
        float v = acc[mi][ni][r] + bv;
        if (do_relu) v = fmaxf(v, 0.f);
        if (outf) outf[(size_t)row * Ntot + col] = v;
        else      outh[(size_t)row * Ntot + col] = (bf16)v;
      }
    }
  }
}

// ---------------- tree gather: hA=bf16(0.5(h[m0]+h[m1])), c likewise -------
__global__ void gather_h(const int* __restrict__ map, const int* __restrict__ flags,
                         int level,
                         const float* __restrict__ h_src, const float* __restrict__ c_src,
                         bf16* __restrict__ hA, float* __restrict__ c_dst)
{
  int n = blockIdx.x, t = threadIdx.x;
  long base = (long)level * 2048 + n * 2;
  int m0, m1;
  if (flags[0]) { m0 = map[base * 2]; m1 = map[base * 2 + 2]; }
  else          { m0 = map[base];     m1 = map[base + 1]; }
  float h0 = m0 ? h_src[(size_t)(m0 - 1) * HIDDEN + t] : 0.f;
  float h1 = m1 ? h_src[(size_t)(m1 - 1) * HIDDEN + t] : 0.f;
  float c0 = m0 ? c_src[(size_t)(m0 - 1) * HIDDEN + t] : 0.f;
  float c1 = m1 ? c_src[(size_t)(m1 - 1) * HIDDEN + t] : 0.f;
  hA[(size_t)n * HIDDEN + t] = (bf16)(0.5f * (h0 + h1));
  c_dst[(size_t)n * HIDDEN + t] = 0.5f * (c0 + c1);
}

// level-15 cell: zero state -> gates = xp2[15] + bhh
__global__ void cell0(const void* __restrict__ xp, int xp_f32,
                      const float* __restrict__ bhh,
                      float* __restrict__ h, float* __restrict__ c)
{
  int n = blockIdx.x, j = threadIdx.x;
  float g[4];
#pragma unroll
  for (int k = 0; k < 4; ++k) {
    size_t idx = (size_t)n * 2048 + k * 512 + j;
    float v = xp_f32 ? ((const float*)xp)[idx] : (float)((const bf16*)xp)[idx];
    g[k] = v + bhh[k * 512 + j];
  }
  float cv = sigmoidf_(g[0]) * tanhf(g[2]);
  h[(size_t)n * HIDDEN + j] = sigmoidf_(g[3]) * tanhf(cv);
  c[(size_t)n * HIDDEN + j] = cv;
}

// ---------------- deterministic batchnorm ----------------
__global__ void bn_reduce_b16(const bf16* __restrict__ x, int rpb, int F,
                              float* __restrict__ partials) {
  int col = threadIdx.x, b = blockIdx.x;
  const bf16* p = x + (size_t)b * rpb * F + col;
  float s = 0.f, q = 0.f;
  for (int r = 0; r < rpb; ++r) { float v = (float)p[(size_t)r * F]; s += v; q += v * v; }
  partials[(size_t)b * 2 * F + col] = s;
  partials[(size_t)b * 2 * F + F + col] = q;
}

__global__ void bn_reduce_f32(const float* __restrict__ x, int rpb, int F,
                              float* __restrict__ partials) {
  int col = threadIdx.x, b = blockIdx.x;
  const float* p = x + (size_t)b * rpb * F + col;
  float s = 0.f, q = 0.f;
  for (int r = 0; r < rpb; ++r) { float v = p[(size_t)r * F]; s += v; q += v * v; }
  partials[(size_t)b * 2 * F + col] = s;
  partials[(size_t)b * 2 * F + F + col] = q;
}

__global__ void bn_final(const float* __restrict__ partials, int nb, int F,
                         const float* __restrict__ g, const float* __restrict__ b,
                         float invB, float* __restrict__ scale, float* __restrict__ shift) {
  int j = threadIdx.x;
  float s = 0.f, q = 0.f;
  for (int i = 0; i < nb; ++i) {
    s += partials[(size_t)i * 2 * F + j];
    q += partials[(size_t)i * 2 * F + F + j];
  }
  float mu = s * invB;
  float var = fmaxf(q * invB - mu * mu, 0.f);
  float sc = g[j] * rsqrtf(var + 1e-5f);
  scale[j] = sc;
  shift[j] = b[j] - sc * mu;
}

__global__ void bn_apply_mid(const bf16* __restrict__ x, const float* __restrict__ scale,
                             const float* __restrict__ shift, int Fmask, size_t total,
                             bf16* __restrict__ out) {
  for (size_t i = blockIdx.x * (size_t)blockDim.x + threadIdx.x; i < total;
       i += (size_t)gridDim.x * blockDim.x) {
    int j = (int)(i & (size_t)Fmask);
    out[i] = (bf16)(scale[j] * (float)x[i] + shift[j]);
  }
}

__global__ void bn_apply_out(const float* __restrict__ x, const float* __restrict__ scale,
                             const float* __restrict__ shift, int Fmask, size_t total,
                             float* __restrict__ out) {
  for (size_t i = blockIdx.x * (size_t)blockDim.x + threadIdx.x; i < total;
       i += (size_t)gridDim.x * blockDim.x) {
    int j = (int)(i & (size_t)Fmask);
    out[i] = scale[j] * x[i] + shift[j];
  }
}

// ---------------------------------------------------------------------------
extern "C" void kernel_launch(void* const* d_in, const int* in_sizes, int n_in,
                              void* d_out, int out_size, void* d_ws, size_t ws_size,
                              hipStream_t stream) {
  const float* operators = (const float*)d_in[0];
  const float* extras    = (const float*)d_in[1];
  const float* conds     = (const float*)d_in[2];
  const int*   mapping   = (const int*)d_in[4];
  const float* b1ih = (const float*)d_in[7];
  const float* b1hh = (const float*)d_in[8];
  const float* condb = (const float*)d_in[10];
  const float* bn1g = (const float*)d_in[11];
  const float* bn1b = (const float*)d_in[12];
  const float* b2ih = (const float*)d_in[15];
  const float* b2hh = (const float*)d_in[16];
  const float* bn2g = (const float*)d_in[17];
  const float* bn2b = (const float*)d_in[18];

  char* ws = (char*)d_ws;
  size_t o = 0;
  auto alloc = [&](size_t bytes) {
    char* p = ws + o;
    o += (bytes + 255) & ~(size_t)255;
    return p;
  };
  bf16* conds_b = (bf16*)alloc((size_t)33554432 * 2);
  bf16* ops_b   = (bf16*)alloc((size_t)524288 * 2);
  bf16* ext_b   = (bf16*)alloc((size_t)524288 * 2);
  bf16* w1ih_b  = (bf16*)alloc((size_t)524288 * 2);
  bf16* w1hh_b  = (bf16*)alloc((size_t)1048576 * 2);
  bf16* condw_b = (bf16*)alloc((size_t)131072 * 2);
  bf16* w2ih_b  = (bf16*)alloc((size_t)655360 * 2);
  bf16* w2hh_b  = (bf16*)alloc((size_t)1048576 * 2);
  bf16* h1[2];
  h1[0] = (bf16*)alloc((size_t)16384 * 512 * 2);
  h1[1] = (bf16*)alloc((size_t)16384 * 512 * 2);
  float* c1 = (float*)alloc((size_t)16384 * 512 * 4);
  bf16* last_relu = (bf16*)alloc((size_t)16384 * 256 * 2);
  bf16* last_bn = (bf16*)alloc((size_t)16384 * 256 * 2);
  float* h2 = (float*)alloc((size_t)1024 * 512 * 4);
  bf16* hA = (bf16*)alloc((size_t)1024 * 512 * 2);
  float* c2a = (float*)alloc((size_t)1024 * 512 * 4);
  float* c2b = (float*)alloc((size_t)1024 * 512 * 4);
  float* partials = (float*)alloc((size_t)64 * 1024 * 4);
  float* scale1 = (float*)alloc(256 * 4);
  float* shift1 = (float*)alloc(256 * 4);
  float* scale2 = (float*)alloc(512 * 4);
  float* shift2 = (float*)alloc(512 * 4);
  int* flags = (int*)alloc(256);

  // xp2: f32 if workspace allows, else bf16
  size_t xp2_elems = (size_t)16384 * 2048;
  int xpf = (o + xp2_elems * 4 <= ws_size) ? 1 : 0;
  void* xp2 = alloc(xp2_elems * (xpf ? 4 : 2));
  float* xp2f = xpf ? (float*)xp2 : nullptr;
  bf16* xp2h = xpf ? nullptr : (bf16*)xp2;

  detect<<<1, 256, 0, stream>>>(mapping, flags);
  cvt8<<<16384, 256, 0, stream>>>(conds, conds_b);
  cvt8<<<256, 256, 0, stream>>>(operators, ops_b);
  cvt8<<<256, 256, 0, stream>>>(extras, ext_b);
  cvt8<<<256, 256, 0, stream>>>((const float*)d_in[5], w1ih_b);
  cvt8<<<512, 256, 0, stream>>>((const float*)d_in[6], w1hh_b);
  cvt8<<<64, 256, 0, stream>>>((const float*)d_in[9], condw_b);
  cvt8<<<320, 256, 0, stream>>>((const float*)d_in[13], w2ih_b);
  cvt8<<<512, 256, 0, stream>>>((const float*)d_in[14], w2hh_b);

  // -------- LSTM1: 8 fused K=768 GEMM+cell steps (kt64 units: 4 + 8) -------
  for (int t = 0; t < 8; ++t) {
    const bf16* hprev = (t == 0) ? nullptr : h1[t & 1];
    cell_gemm<4><<<dim3(128, 16), 256, 0, stream>>>(
        conds_b, t * 256, 2048, 4,
        hprev, 512, (t == 0) ? 0 : 8,
        w1ih_b, 256, w1hh_b, 512,
        b1ih, b1hh,
        nullptr, 0,
        (t == 0) ? nullptr : c1, c1, h1[(t + 1) & 1], nullptr);
  }

  // -------- last = relu(h1 @ condW^T + condb); BN1 --------
  plain_gemm<<<dim3(128, 2), 256, 0, stream>>>(
      h1[0], 512, 16, nullptr, 0, 0, nullptr, 0, 0,
      condw_b, 512, condb, 1, last_relu, nullptr, 256);
  bn_reduce_b16<<<64, 256, 0, stream>>>(last_relu, 256, 256, partials);
  bn_final<<<1, 256, 0, stream>>>(partials, 64, 256, bn1g, bn1b, 1.f / 16384.f, scale1, shift1);
  bn_apply_mid<<<1024, 256, 0, stream>>>(last_relu, scale1, shift1, 255,
                                         (size_t)16384 * 256, last_bn);

  // -------- xp2 = concat(ops, extras, last_bn) @ W2ih^T + b2ih --------
  plain_gemm<<<dim3(128, 16), 256, 0, stream>>>(
      ops_b, 32, 1, ext_b, 32, 1, last_bn, 256, 8,
      w2ih_b, 320, b2ih, 0, xp2h, xp2f, 2048);

  // -------- LSTM2 tree (K=512, 64-row tiles, 256 blocks) --------
  size_t lvl_sz = (size_t)1024 * 2048;
  const void* xp15 = xpf ? (const void*)(xp2f + 15 * lvl_sz) : (const void*)(xp2h + 15 * lvl_sz);
  cell0<<<1024, 512, 0, stream>>>(xp15, xpf, b2hh, h2, c2a);
  for (int idx = 14; idx >= 0; --idx) {
    gather_h<<<1024, 512, 0, stream>>>(mapping, flags, idx, h2, c2a, hA, c2b);
    const void* xpl = xpf ? (const void*)(xp2f + idx * lvl_sz) : (const void*)(xp2h + idx * lvl_sz);
    cell_gemm<2><<<dim3(16, 16), 256, 0, stream>>>(
        hA, 0, 512, 8,
        nullptr, 0, 0,
        w2hh_b, 512, nullptr, 0,
        b2hh, nullptr,
        xpl, xpf,
        c2b, c2a, nullptr, h2);
  }

  // -------- BN2 -> output --------
  bn_reduce_f32<<<16, 512, 0, stream>>>(h2, 64, 512, partials);
  bn_final<<<1, 512, 0, stream>>>(partials, 16, 512, bn2g, bn2b, 1.f / 1024.f, scale2, shift2);
  bn_apply_out<<<512, 256, 0, stream>>>(h2, scale2, shift2, 511,
                                        (size_t)1024 * 512, (float*)d_out);
}